// Round 1
// baseline (5263.737 us; speedup 1.0000x reference)
//
#include <hip/hip_runtime.h>
#include <math.h>

#define TT   64    // T_in == T_out
#define BB   64    // batch
#define HH   256   // hidden
#define VV   32000 // vocab
#define NG   1024  // 4*H gate rows
#define KK   256   // GEMM K (always H)

// ---------------- embedding gather ----------------
// tokens [T,B] int32; out X [T,B,H]. shifted=1: dec_in = [0, targets[:-1]]
__global__ void embed_kernel(const int* __restrict__ tok, const float* __restrict__ tab,
                             float* __restrict__ X, int shifted) {
  int blk = blockIdx.x;          // t*B + b
  int t = blk >> 6, b = blk & 63;
  int id;
  if (shifted) id = (t == 0) ? 0 : tok[(t - 1) * BB + b];
  else         id = tok[t * BB + b];
  const float4* src = (const float4*)(tab + (long)id * HH);
  float4* dst = (float4*)(X + (long)blk * HH);
  dst[threadIdx.x] = src[threadIdx.x];   // 64 threads * float4 = 256 floats
}

// ---------------- weight packing ----------------
// Row permutation r' = 4*j + g  <->  r = g*256 + j  (gate-interleave per hidden unit)
// Wpk[L][r'][k] = Wih[L][r][k]; bpk[L][r'] = bih[r]+bhh[r]
__global__ void pack_wih(const float* __restrict__ eW, const float* __restrict__ dW,
                         const float* __restrict__ ebi, const float* __restrict__ ebh,
                         const float* __restrict__ dbi, const float* __restrict__ dbh,
                         float* __restrict__ Wpk, float* __restrict__ bpk) {
  int L = blockIdx.y;            // 0..5
  int rp = blockIdx.x;           // 0..1023
  int j = rp >> 2, g = rp & 3;
  int r = g * HH + j;
  const float* src = (L < 3 ? eW + (long)L * NG * HH : dW + (long)(L - 3) * NG * HH) + (long)r * HH;
  float* dst = Wpk + ((long)L * NG + rp) * HH;
  ((float4*)dst)[threadIdx.x] = ((const float4*)src)[threadIdx.x];  // 64 thr * float4
  if (threadIdx.x == 0) {
    const float* bi = (L < 3 ? ebi + L * NG : dbi + (L - 3) * NG);
    const float* bh = (L < 3 ? ebh + L * NG : dbh + (L - 3) * NG);
    bpk[(long)L * NG + rp] = bi[r] + bh[r];
  }
}

// WT[L][k][r'] = Whh[L][g*256+j][k]  (transposed + gate-interleaved)
__global__ void pack_whhT(const float* __restrict__ eW, const float* __restrict__ dW,
                          float* __restrict__ WT) {
  int L = blockIdx.y;            // 0..5
  int k = blockIdx.x;            // 0..255
  const float* src = (L < 3 ? eW + (long)L * NG * HH : dW + (long)(L - 3) * NG * HH);
  float* dst = WT + ((long)L * HH + k) * NG;
  int t = threadIdx.x;           // 0..255 -> j = t, g = 0..3
  float4 v;
  v.x = src[((long)(0 * HH + t)) * HH + k];
  v.y = src[((long)(1 * HH + t)) * HH + k];
  v.z = src[((long)(2 * HH + t)) * HH + k];
  v.w = src[((long)(3 * HH + t)) * HH + k];
  ((float4*)dst)[t] = v;
}

// ---------------- fp32 tiled GEMM: C[M,N] = A[M,256] * B[N,256]^T + bias ----------------
// 64x64 tile, 256 threads, 4x4 accum/thread. Optional fused per-tile row-argmax.
#define KC 64
__device__ inline unsigned long long shfl_xor_u64(unsigned long long v, int m) {
  unsigned lo = (unsigned)v, hi = (unsigned)(v >> 32);
  lo = __shfl_xor(lo, m);
  hi = __shfl_xor(hi, m);
  return ((unsigned long long)hi << 32) | lo;
}

__global__ __launch_bounds__(256) void gemm_bias(
    const float* __restrict__ A, const float* __restrict__ B,
    const float* __restrict__ bias, float* __restrict__ C,
    int N, unsigned long long* __restrict__ amax) {
  __shared__ float As[KC][64 + 4];   // stored transposed: As[k][m]; row=272B keeps 16B align
  __shared__ float Bs[KC][64 + 4];
  int tn = blockIdx.x, tm = blockIdx.y;
  int m0 = tm * 64, n0 = tn * 64;
  int t = threadIdx.x;
  int tx = t & 15, ty = t >> 4;
  float acc[4][4] = {};
  for (int kc = 0; kc < KK; kc += KC) {
    #pragma unroll
    for (int i = 0; i < 4; i++) {
      int row = (t >> 4) + 16 * i;       // 0..63
      int col = (t & 15) * 4;            // 0..60
      float4 a = *(const float4*)(A + (long)(m0 + row) * KK + kc + col);
      As[col + 0][row] = a.x; As[col + 1][row] = a.y;
      As[col + 2][row] = a.z; As[col + 3][row] = a.w;
      float4 b = *(const float4*)(B + (long)(n0 + row) * KK + kc + col);
      Bs[col + 0][row] = b.x; Bs[col + 1][row] = b.y;
      Bs[col + 2][row] = b.z; Bs[col + 3][row] = b.w;
    }
    __syncthreads();
    #pragma unroll 8
    for (int kk = 0; kk < KC; kk++) {
      float4 a4 = *(const float4*)&As[kk][ty * 4];
      float4 b4 = *(const float4*)&Bs[kk][tx * 4];
      acc[0][0] += a4.x * b4.x; acc[0][1] += a4.x * b4.y; acc[0][2] += a4.x * b4.z; acc[0][3] += a4.x * b4.w;
      acc[1][0] += a4.y * b4.x; acc[1][1] += a4.y * b4.y; acc[1][2] += a4.y * b4.z; acc[1][3] += a4.y * b4.w;
      acc[2][0] += a4.z * b4.x; acc[2][1] += a4.z * b4.y; acc[2][2] += a4.z * b4.z; acc[2][3] += a4.z * b4.w;
      acc[3][0] += a4.w * b4.x; acc[3][1] += a4.w * b4.y; acc[3][2] += a4.w * b4.z; acc[3][3] += a4.w * b4.w;
    }
    __syncthreads();
  }
  float4 bv = *(const float4*)(bias + n0 + tx * 4);
  #pragma unroll
  for (int i = 0; i < 4; i++) {
    int m = m0 + ty * 4 + i;
    float4 o;
    o.x = acc[i][0] + bv.x; o.y = acc[i][1] + bv.y;
    o.z = acc[i][2] + bv.z; o.w = acc[i][3] + bv.w;
    *(float4*)(C + (long)m * N + n0 + tx * 4) = o;
    if (amax) {
      // local argmax over this thread's 4 cols (strict > keeps lowest index on tie)
      float best = o.x; int bi = n0 + tx * 4;
      if (o.y > best) { best = o.y; bi = n0 + tx * 4 + 1; }
      if (o.z > best) { best = o.z; bi = n0 + tx * 4 + 2; }
      if (o.w > best) { best = o.w; bi = n0 + tx * 4 + 3; }
      unsigned uo = __float_as_uint(best);
      uo = (uo >> 31) ? ~uo : (uo | 0x80000000u);   // orderable float bits
      unsigned long long key = ((unsigned long long)uo << 32) | (unsigned)(0xFFFFFFFFu - bi);
      #pragma unroll
      for (int s = 1; s < 16; s <<= 1) {
        unsigned long long o2 = shfl_xor_u64(key, s);
        if (o2 > key) key = o2;
      }
      if (tx == 0) amax[(long)m * gridDim.x + tn] = key;
    }
  }
}

// reduce per-row tile keys -> float index
__global__ void argmax_fin(const unsigned long long* __restrict__ amax,
                           float* __restrict__ out1, int ntiles) {
  int row = blockIdx.x;
  int t = threadIdx.x;   // 64
  unsigned long long key = 0ull;
  for (int c = t; c < ntiles; c += 64) {
    unsigned long long k = amax[(long)row * ntiles + c];
    if (k > key) key = k;
  }
  #pragma unroll
  for (int s = 1; s < 64; s <<= 1) {
    unsigned long long o = shfl_xor_u64(key, s);
    if (o > key) key = o;
  }
  if (t == 0) out1[row] = (float)(0xFFFFFFFFu - (unsigned)(key & 0xFFFFFFFFu));
}

// ---------------- LSTM recurrence: one workgroup per batch, no cross-WG sync ----------------
// G [T,B,1024] gate-interleaved pre-gates (x*Wih^T + b); WT [256,1024] packed Whh^T.
__global__ __launch_bounds__(256) void lstm_recur(
    const float* __restrict__ G, const float* __restrict__ WT,
    const float* __restrict__ h0, int h0s,
    const float* __restrict__ c0, int c0s,
    float* __restrict__ Hout, float* __restrict__ hfin, float* __restrict__ cfin) {
  __shared__ float h_lds[HH];
  int b = blockIdx.x;
  int j = threadIdx.x;   // hidden unit 0..255
  float c = c0[b * c0s + j];
  h_lds[j] = h0[b * h0s + j];
  __syncthreads();
  const float4* WT4 = (const float4*)WT;   // [256][256] float4 rows
  for (int t = 0; t < TT; t++) {
    const float4* g4p = (const float4*)(G + ((long)(t * BB + b)) * NG);
    float4 acc = g4p[j];                   // (i,f,g,o) pre-gates of unit j
    #pragma unroll 4
    for (int k = 0; k < HH; k += 4) {
      float4 h4 = *(const float4*)&h_lds[k];
      float4 w0 = WT4[(long)(k + 0) * HH + j];
      float4 w1 = WT4[(long)(k + 1) * HH + j];
      float4 w2 = WT4[(long)(k + 2) * HH + j];
      float4 w3 = WT4[(long)(k + 3) * HH + j];
      acc.x += h4.x * w0.x; acc.y += h4.x * w0.y; acc.z += h4.x * w0.z; acc.w += h4.x * w0.w;
      acc.x += h4.y * w1.x; acc.y += h4.y * w1.y; acc.z += h4.y * w1.z; acc.w += h4.y * w1.w;
      acc.x += h4.z * w2.x; acc.y += h4.z * w2.y; acc.z += h4.z * w2.z; acc.w += h4.z * w2.w;
      acc.x += h4.w * w3.x; acc.y += h4.w * w3.y; acc.z += h4.w * w3.z; acc.w += h4.w * w3.w;
    }
    __syncthreads();                       // all threads done reading h_lds
    float i_ = 1.f / (1.f + expf(-acc.x));
    float f_ = 1.f / (1.f + expf(-acc.y));
    float g_ = tanhf(acc.z);
    float o_ = 1.f / (1.f + expf(-acc.w));
    c = f_ * c + i_ * g_;
    float hn = o_ * tanhf(c);
    h_lds[j] = hn;
    Hout[((long)(t * BB + b)) * HH + j] = hn;
    __syncthreads();
  }
  hfin[b * HH + j] = h_lds[j];
  cfin[b * HH + j] = c;
}

// ---------------- host orchestration ----------------
extern "C" void kernel_launch(void* const* d_in, const int* in_sizes, int n_in,
                              void* d_out, int out_size, void* d_ws, size_t ws_size,
                              hipStream_t stream) {
  const int*   inputs  = (const int*)d_in[0];
  const int*   targets = (const int*)d_in[1];
  const float* enc_emb = (const float*)d_in[2];
  const float* enc_Wih = (const float*)d_in[3];
  const float* enc_Whh = (const float*)d_in[4];
  const float* enc_bih = (const float*)d_in[5];
  const float* enc_bhh = (const float*)d_in[6];
  const float* hidden0 = (const float*)d_in[7];
  const float* cell0   = (const float*)d_in[8];
  const float* dec_emb = (const float*)d_in[9];
  const float* dec_Wih = (const float*)d_in[10];
  const float* dec_Whh = (const float*)d_in[11];
  const float* dec_bih = (const float*)d_in[12];
  const float* dec_bhh = (const float*)d_in[13];
  const float* fc_W    = (const float*)d_in[14];
  const float* fc_b    = (const float*)d_in[15];

  float* out0 = (float*)d_out;
  float* out1 = out0 + (long)TT * BB * VV;

  float* X   = (float*)d_ws;                 // [4096,256]   4 MB  (layer I/O sequence)
  float* G   = X   + (long)4096 * 256;       // [4096,1024] 16 MB  (pre-gates)
  float* Wpk = G   + (long)4096 * 1024;      // [6,1024,256] 6 MB
  float* WT  = Wpk + (long)6 * 1024 * 256;   // [6,256,1024] 6 MB
  float* bpk = WT  + (long)6 * 256 * 1024;   // [6,1024]
  float* hst = bpk + 6 * 1024;               // enc final h [3,64,256]
  float* cst = hst + 3 * 64 * 256;           // enc final c [3,64,256]
  float* hsc = cst + 3 * 64 * 256;           // dec scratch h
  float* csc = hsc + 64 * 256;               // dec scratch c
  unsigned long long* amax = (unsigned long long*)G;  // overlay: G dead before FC

  // weight packing (all 6 layers) + encoder embedding
  embed_kernel<<<4096, 64, 0, stream>>>(inputs, enc_emb, X, 0);
  pack_wih<<<dim3(1024, 6), 64, 0, stream>>>(enc_Wih, dec_Wih, enc_bih, enc_bhh,
                                             dec_bih, dec_bhh, Wpk, bpk);
  pack_whhT<<<dim3(256, 6), 256, 0, stream>>>(enc_Whh, dec_Whh, WT);

  // encoder: 3 layers
  for (int l = 0; l < 3; l++) {
    gemm_bias<<<dim3(16, 64), 256, 0, stream>>>(X, Wpk + (long)l * NG * HH,
                                                bpk + l * NG, G, NG, nullptr);
    lstm_recur<<<64, 256, 0, stream>>>(G, WT + (long)l * HH * NG,
                                       hidden0 + l * HH, 0, cell0 + l * HH, 0,
                                       X, hst + (long)l * BB * HH, cst + (long)l * BB * HH);
  }

  // decoder: teacher-forced input embedding, 3 layers seeded from encoder finals
  embed_kernel<<<4096, 64, 0, stream>>>(targets, dec_emb, X, 1);
  for (int l = 0; l < 3; l++) {
    gemm_bias<<<dim3(16, 64), 256, 0, stream>>>(X, Wpk + (long)(3 + l) * NG * HH,
                                                bpk + (3 + l) * NG, G, NG, nullptr);
    lstm_recur<<<64, 256, 0, stream>>>(G, WT + (long)(3 + l) * HH * NG,
                                       hst + (long)l * BB * HH, HH,
                                       cst + (long)l * BB * HH, HH,
                                       X, hsc, csc);
  }

  // FC head + fused per-tile argmax, then finalize
  gemm_bias<<<dim3(500, 64), 256, 0, stream>>>(X, fc_W, fc_b, out0, VV, amax);
  argmax_fin<<<4096, 64, 0, stream>>>(amax, out1, 500);
}